// Round 4
// baseline (76.614 us; speedup 1.0000x reference)
//
#include <hip/hip_runtime.h>

// KalmanStaticFilter: per-row linear recurrence s_{t+1} = M s_t + c z_t
//   M = [[1-a-b, 1], [-b, 1]], output x_t = (1-a) p_t + a z_t
// R3: split each row into two INDEPENDENT half-row waves using contraction
// (rho(M)=0.9941, 0.9941^2048 ~ 5e-6): half-1 warm-starts 2048 elems early
// from seed (z,0). 2 same-phase waves per 128-thr block, W=1024 sections,
// 32 waves/CU target. Affine-map Kogge-Stone scan per section.

#define A_CONST 0.85f
#define B_CONST 0.005f

typedef float vfloat4 __attribute__((ext_vector_type(4)));  // for nontemporal store

constexpr int ROWS      = 4096;
constexpr int T         = 8192;
constexpr int W         = 1024;     // section width
constexpr int L         = 16;       // per-lane chunk length
constexpr int STRIDE    = 17;       // padded LDS chunk stride
constexpr int HALF      = T / 2;    // 4096
constexpr int NSEC_REAL = HALF / W; // 4
constexpr int WARM      = 2;        // warm-up sections for half 1 (2048 elems)

__global__ __launch_bounds__(128, 8)
void kalman_kernel(const float* __restrict__ Z, float* __restrict__ X) {
    const int wid  = threadIdx.x >> 6;
    const int lane = threadIdx.x & 63;
    const int g    = blockIdx.x * 2 + wid;   // global wave id, 0..8191
    const int half = g >> 12;                // 0: first 4096 waves, 1: rest
    const int row  = g & (ROWS - 1);

    __shared__ float lds[2][64 * STRIDE];    // 2 x 4352 B
    float* buf = lds[wid];

    const float* Zr = Z + (size_t)row * T;
    float*       Xr = X + (size_t)row * T;

    const int nWarm = half ? WARM : 0;               // uniform across block
    const int nSec  = nWarm + NSEC_REAL;
    const int start = half ? (HALF - WARM * W) : 0;  // 2048 or 0
    const float* Zs = Zr + start;
    float*       Xs = Xr + start;

    // A16 = M^16 via repeated squaring (f64 once, negligible)
    double a00 = 1.0 - (double)A_CONST - (double)B_CONST, a01 = 1.0;
    double a10 = -(double)B_CONST,                        a11 = 1.0;
    #pragma unroll
    for (int i = 0; i < 4; ++i) {
        double n00 = a00*a00 + a01*a10;
        double n01 = a00*a01 + a01*a11;
        double n10 = a10*a00 + a11*a10;
        double n11 = a10*a01 + a11*a11;
        a00 = n00; a01 = n01; a10 = n10; a11 = n11;
    }
    const float A16_00 = (float)a00, A16_01 = (float)a01;
    const float A16_10 = (float)a10, A16_11 = (float)a11;

    // seed: exact for half 0 (p0 = Z[row][0]); warm-start for half 1
    float ps = Zs[0];
    float vs = 0.0f;

    // prologue: prefetch section 0 into registers
    float4 r[4];
    {
        const float4* src = (const float4*)Zs;
        #pragma unroll
        for (int i = 0; i < 4; ++i) r[i] = src[i * 64 + lane];
    }

    for (int s = 0; s < nSec; ++s) {
        // ---- stage prefetched registers into LDS (chunk-transpose layout) ----
        #pragma unroll
        for (int i = 0; i < 4; ++i) {
            int f = i * 64 + lane;
            int c = f >> 2;                // chunk (16 elems = 4 float4)
            int j = (f & 3) << 2;          // pos within chunk
            float* p = buf + c * STRIDE + j;
            p[0] = r[i].x; p[1] = r[i].y; p[2] = r[i].z; p[3] = r[i].w;
        }

        // ---- issue next section's loads (in flight under compute) ----
        if (s + 1 < nSec) {
            const float4* src = (const float4*)(Zs + (s + 1) * W);
            #pragma unroll
            for (int i = 0; i < 4; ++i) r[i] = src[i * 64 + lane];
        }

        __syncthreads();

        // ---- pass A: per-lane chunk offset from s=(0,0); keep z in regs ----
        float c16[L];
        float bp, bv;
        {
            float p = 0.0f, v = 0.0f;
            const float* zc = buf + lane * STRIDE;
            #pragma unroll
            for (int j = 0; j < L; ++j) {
                float z    = zc[j];
                c16[j]     = z;
                float diff = z - p;
                float x    = p + A_CONST * diff;
                v += B_CONST * diff;
                p  = x + v;
            }
            bp = p; bv = v;
        }

        // ---- Kogge-Stone inclusive scan of affine maps across 64 lanes ----
        float sA00 = A16_00, sA01 = A16_01, sA10 = A16_10, sA11 = A16_11;
        float sb0 = bp, sb1 = bv;
        #pragma unroll
        for (int d = 1; d < 64; d <<= 1) {
            float oA00 = __shfl_up(sA00, d);
            float oA01 = __shfl_up(sA01, d);
            float oA10 = __shfl_up(sA10, d);
            float oA11 = __shfl_up(sA11, d);
            float ob0  = __shfl_up(sb0,  d);
            float ob1  = __shfl_up(sb1,  d);
            if (lane >= d) {
                float n00 = sA00*oA00 + sA01*oA10;
                float n01 = sA00*oA01 + sA01*oA11;
                float n10 = sA10*oA00 + sA11*oA10;
                float n11 = sA10*oA01 + sA11*oA11;
                float nb0 = sA00*ob0 + sA01*ob1 + sb0;
                float nb1 = sA10*ob0 + sA11*ob1 + sb1;
                sA00 = n00; sA01 = n01; sA10 = n10; sA11 = n11;
                sb0 = nb0; sb1 = nb1;
            }
        }

        // exclusive prefix (lane 0 = identity)
        float eA00 = __shfl_up(sA00, 1);
        float eA01 = __shfl_up(sA01, 1);
        float eA10 = __shfl_up(sA10, 1);
        float eA11 = __shfl_up(sA11, 1);
        float eb0  = __shfl_up(sb0,  1);
        float eb1  = __shfl_up(sb1,  1);
        if (lane == 0) { eA00 = 1.f; eA01 = 0.f; eA10 = 0.f; eA11 = 1.f; eb0 = 0.f; eb1 = 0.f; }

        // lane-63 inclusive = full section map (next section's start state)
        float iA00 = __shfl(sA00, 63);
        float iA01 = __shfl(sA01, 63);
        float iA10 = __shfl(sA10, 63);
        float iA11 = __shfl(sA11, 63);
        float ib0  = __shfl(sb0,  63);
        float ib1  = __shfl(sb1,  63);

        // ---- pass B (real sections only): replay chunk, write x to LDS ----
        if (s >= nWarm) {
            float p = eA00*ps + eA01*vs + eb0;
            float v = eA10*ps + eA11*vs + eb1;
            float* zc = buf + lane * STRIDE;
            #pragma unroll
            for (int j = 0; j < L; ++j) {
                float z    = c16[j];
                float diff = z - p;
                float x    = p + A_CONST * diff;
                v += B_CONST * diff;
                p  = x + v;
                zc[j] = x;
            }
        }

        // advance section-start state (warm-up and real)
        {
            float np = iA00*ps + iA01*vs + ib0;
            float nv = iA10*ps + iA11*vs + ib1;
            ps = np; vs = nv;
        }

        __syncthreads();

        // ---- unload (real sections only): coalesced nontemporal stores ----
        if (s >= nWarm) {
            vfloat4* dst = (vfloat4*)(Xs + s * W);
            #pragma unroll
            for (int i = 0; i < 4; ++i) {
                int f = i * 64 + lane;
                int c = f >> 2;
                int j = (f & 3) << 2;
                const float* p = buf + c * STRIDE + j;
                vfloat4 v4 = { p[0], p[1], p[2], p[3] };
                __builtin_nontemporal_store(v4, dst + f);
            }
            __syncthreads();   // protect buf before next staging
        }
    }
}

extern "C" void kernel_launch(void* const* d_in, const int* in_sizes, int n_in,
                              void* d_out, int out_size, void* d_ws, size_t ws_size,
                              hipStream_t stream) {
    const float* Z = (const float*)d_in[0];
    float*       X = (float*)d_out;
    dim3 grid(ROWS), block(128);   // 4096 blocks x 2 waves = 8192 half-row waves
    hipLaunchKernelGGL(kalman_kernel, grid, block, 0, stream, Z, X);
}

// Round 5
// 45.256 us; speedup vs baseline: 1.6929x; 1.6929x over previous
//
#include <hip/hip_runtime.h>

// KalmanStaticFilter: per-row linear recurrence s_{t+1} = M s_t + c z_t
//   M = [[1-a-b, 1], [-b, 1]], c = [a+b, b], output x_t = p_t + a(z_t - p_t)
// R5: exact full-row (no half-split; R4's warm-start doubled HBM traffic and
// regressed). 2 waves per row, W=4096 sections, L=32/STRIDE=33 LDS layout
// (R2-proven zero-conflict). Constant-matrix Kogge-Stone scan: chunk matrix
// is always A32=M^32, so stage-d combine uses wave-uniform A32^d (2 shuffles
// + 4 FMA per stage). Per-lane entry state via precomputed A32^lane.

#define A_CONST 0.85f
#define B_CONST 0.005f

typedef float vfloat4 __attribute__((ext_vector_type(4)));  // nontemporal store

constexpr int ROWS   = 4096;
constexpr int T      = 8192;
constexpr int W      = 4096;     // section width (per 2-wave block)
constexpr int L      = 32;       // per-lane chunk length
constexpr int NSEC   = T / W;    // 2
constexpr int STRIDE = 33;       // padded LDS chunk stride (zero-conflict, R2)
constexpr int NCHUNK = W / L;    // 128

__global__ __launch_bounds__(128, 4)
void kalman_kernel(const float* __restrict__ Z, float* __restrict__ X) {
    const int tid  = threadIdx.x;        // 0..127
    const int wid  = tid >> 6;           // wave 0/1
    const int lane = tid & 63;
    const int row  = blockIdx.x;

    __shared__ float buf[NCHUNK * STRIDE];   // 4224 floats = 16896 B
    __shared__ float scr[4];                 // cross-wave combine (I0, I1)

    const float* Zr = Z + (size_t)row * T;
    float*       Xr = X + (size_t)row * T;

    // ---- f64 precompute (once): G[k] = M^(32*2^k), k=0..6 ----
    double m00 = 1.0 - (double)A_CONST - (double)B_CONST, m01 = 1.0;
    double m10 = -(double)B_CONST,                        m11 = 1.0;
    #pragma unroll
    for (int i = 0; i < 5; ++i) {          // -> M^32
        double n00 = m00*m00 + m01*m10, n01 = m00*m01 + m01*m11;
        double n10 = m10*m00 + m11*m10, n11 = m10*m01 + m11*m11;
        m00 = n00; m01 = n01; m10 = n10; m11 = n11;
    }
    double g00[7], g01[7], g10[7], g11[7];
    g00[0] = m00; g01[0] = m01; g10[0] = m10; g11[0] = m11;
    #pragma unroll
    for (int k = 1; k < 7; ++k) {
        g00[k] = g00[k-1]*g00[k-1] + g01[k-1]*g10[k-1];
        g01[k] = g00[k-1]*g01[k-1] + g01[k-1]*g11[k-1];
        g10[k] = g10[k-1]*g00[k-1] + g11[k-1]*g10[k-1];
        g11[k] = g10[k-1]*g01[k-1] + g11[k-1]*g11[k-1];
    }
    // f32 scan-stage constants A32^(2^k), k=0..5
    float sc00[6], sc01[6], sc10[6], sc11[6];
    #pragma unroll
    for (int k = 0; k < 6; ++k) {
        sc00[k] = (float)g00[k]; sc01[k] = (float)g01[k];
        sc10[k] = (float)g10[k]; sc11[k] = (float)g11[k];
    }
    // A2048 = M^2048 (per-wave span map)
    const float w00 = (float)g00[6], w01 = (float)g01[6];
    const float w10 = (float)g10[6], w11 = (float)g11[6];
    // per-lane matrix A32^lane via bit product (powers of M commute)
    double l00 = 1.0, l01 = 0.0, l10 = 0.0, l11 = 1.0;
    #pragma unroll
    for (int k = 0; k < 6; ++k) {
        if ((lane >> k) & 1) {
            double n00 = g00[k]*l00 + g01[k]*l10, n01 = g00[k]*l01 + g01[k]*l11;
            double n10 = g10[k]*l00 + g11[k]*l10, n11 = g10[k]*l01 + g11[k]*l11;
            l00 = n00; l01 = n01; l10 = n10; l11 = n11;
        }
    }
    const float La00 = (float)l00, La01 = (float)l01;
    const float La10 = (float)l10, La11 = (float)l11;

    // section-start state (tracked redundantly by every thread)
    float ps = Zr[0];
    float vs = 0.0f;

    // prologue: prefetch section 0 (8 float4/lane, coalesced)
    float4 r[8];
    {
        const float4* src = (const float4*)Zr;
        #pragma unroll
        for (int i = 0; i < 8; ++i) r[i] = src[i * 128 + tid];
    }

    for (int s = 0; s < NSEC; ++s) {
        // ---- stage prefetched regs into LDS (chunk-transpose, R2 pattern) ----
        #pragma unroll
        for (int i = 0; i < 8; ++i) {
            int f = i * 128 + tid;
            int c = f >> 3;                 // chunk
            int j = (f & 7) << 2;           // pos within chunk
            float* p = buf + c * STRIDE + j;
            p[0] = r[i].x; p[1] = r[i].y; p[2] = r[i].z; p[3] = r[i].w;
        }

        // ---- issue next section's loads (in flight under compute) ----
        if (s + 1 < NSEC) {
            const float4* src = (const float4*)(Zr + (s + 1) * W);
            #pragma unroll
            for (int i = 0; i < 8; ++i) r[i] = src[i * 128 + tid];
        }

        __syncthreads();

        // ---- pass A: per-lane chunk offset from s=(0,0); keep z in regs ----
        float c32[L];
        float bp, bv;
        {
            float p = 0.0f, v = 0.0f;
            const float* zc = buf + tid * STRIDE;   // chunk index == tid
            #pragma unroll
            for (int j = 0; j < L; ++j) {
                float z    = zc[j];
                c32[j]     = z;
                float diff = z - p;
                float x    = p + A_CONST * diff;
                v += B_CONST * diff;
                p  = x + v;
            }
            bp = p; bv = v;
        }

        // ---- constant-matrix Kogge-Stone scan of offsets (own wave) ----
        float sb0 = bp, sb1 = bv;
        #pragma unroll
        for (int k = 0; k < 6; ++k) {
            const int d = 1 << k;
            float ob0 = __shfl_up(sb0, d);
            float ob1 = __shfl_up(sb1, d);
            if (lane >= d) {
                sb0 = sc00[k]*ob0 + sc01[k]*ob1 + sb0;
                sb1 = sc10[k]*ob0 + sc11[k]*ob1 + sb1;
            }
        }

        // exclusive prefix offset
        float eb0 = __shfl_up(sb0, 1);
        float eb1 = __shfl_up(sb1, 1);
        if (lane == 0) { eb0 = 0.0f; eb1 = 0.0f; }

        // wave-inclusive total -> LDS scratch
        float i0 = __shfl(sb0, 63);
        float i1 = __shfl(sb1, 63);
        if (lane == 0) { scr[wid * 2] = i0; scr[wid * 2 + 1] = i1; }
        __syncthreads();

        const float I00 = scr[0], I01 = scr[1];   // wave 0 total
        const float I10 = scr[2], I11 = scr[3];   // wave 1 total

        // wave entry state S_w (wave1 = A2048*s_sec + I0)
        const float T0 = w00*ps + w01*vs + I00;   // = S_1
        const float T1 = w10*ps + w11*vs + I01;
        const float S0 = wid ? T0 : ps;
        const float S1 = wid ? T1 : vs;
        // next section-start state: A2048*S_1 + I_1
        const float np = w00*T0 + w01*T1 + I10;
        const float nv = w10*T0 + w11*T1 + I11;

        // per-lane entry: A32^lane * S_w + exclusive offset
        float p = La00*S0 + La01*S1 + eb0;
        float v = La10*S0 + La11*S1 + eb1;

        // ---- pass B: replay chunk from regs, write x to LDS ----
        {
            float* zc = buf + tid * STRIDE;
            #pragma unroll
            for (int j = 0; j < L; ++j) {
                float z    = c32[j];
                float diff = z - p;
                float x    = p + A_CONST * diff;
                v += B_CONST * diff;
                p  = x + v;
                zc[j] = x;
            }
        }

        __syncthreads();

        // ---- unload: coalesced nontemporal float4 stores ----
        {
            vfloat4* dst = (vfloat4*)(Xr + s * W);
            #pragma unroll
            for (int i = 0; i < 8; ++i) {
                int f = i * 128 + tid;
                int c = f >> 3;
                int j = (f & 7) << 2;
                const float* q = buf + c * STRIDE + j;
                vfloat4 v4 = { q[0], q[1], q[2], q[3] };
                __builtin_nontemporal_store(v4, dst + f);
            }
        }

        __syncthreads();   // protect buf before next section's staging

        ps = np; vs = nv;
    }
}

extern "C" void kernel_launch(void* const* d_in, const int* in_sizes, int n_in,
                              void* d_out, int out_size, void* d_ws, size_t ws_size,
                              hipStream_t stream) {
    const float* Z = (const float*)d_in[0];
    float*       X = (float*)d_out;
    dim3 grid(ROWS), block(128);
    hipLaunchKernelGGL(kalman_kernel, grid, block, 0, stream, Z, X);
}

// Round 6
// 45.120 us; speedup vs baseline: 1.6980x; 1.0030x over previous
//
#include <hip/hip_runtime.h>

// KalmanStaticFilter: per-row linear recurrence s_{t+1} = M s_t + c z_t
//   M = [[1-a-b, 1], [-b, 1]], c = [a+b, b], output x_t = p_t + a(z_t - p_t)
// R6: R5 structure unchanged (2 waves/row, W=4096, L=32/STRIDE=33,
// constant-matrix scan). Single change: X stores via inline-asm
// global_store_dwordx4 sc0 sc1 nt -> no L3 allocation for the output
// stream, keeping Z fully Infinity-Cache-resident across replays.

#define A_CONST 0.85f
#define B_CONST 0.005f

typedef float vfloat4 __attribute__((ext_vector_type(4)));

constexpr int ROWS   = 4096;
constexpr int T      = 8192;
constexpr int W      = 4096;     // section width (per 2-wave block)
constexpr int L      = 32;       // per-lane chunk length
constexpr int NSEC   = T / W;    // 2
constexpr int STRIDE = 33;       // padded LDS chunk stride (zero-conflict)
constexpr int NCHUNK = W / L;    // 128

__global__ __launch_bounds__(128, 4)
void kalman_kernel(const float* __restrict__ Z, float* __restrict__ X) {
    const int tid  = threadIdx.x;        // 0..127
    const int wid  = tid >> 6;           // wave 0/1
    const int lane = tid & 63;
    const int row  = blockIdx.x;

    __shared__ float buf[NCHUNK * STRIDE];   // 16896 B
    __shared__ float scr[4];                 // cross-wave combine

    const float* Zr = Z + (size_t)row * T;
    float*       Xr = X + (size_t)row * T;

    // ---- f64 precompute (once): G[k] = M^(32*2^k), k=0..6 ----
    double m00 = 1.0 - (double)A_CONST - (double)B_CONST, m01 = 1.0;
    double m10 = -(double)B_CONST,                        m11 = 1.0;
    #pragma unroll
    for (int i = 0; i < 5; ++i) {          // -> M^32
        double n00 = m00*m00 + m01*m10, n01 = m00*m01 + m01*m11;
        double n10 = m10*m00 + m11*m10, n11 = m10*m01 + m11*m11;
        m00 = n00; m01 = n01; m10 = n10; m11 = n11;
    }
    double g00[7], g01[7], g10[7], g11[7];
    g00[0] = m00; g01[0] = m01; g10[0] = m10; g11[0] = m11;
    #pragma unroll
    for (int k = 1; k < 7; ++k) {
        g00[k] = g00[k-1]*g00[k-1] + g01[k-1]*g10[k-1];
        g01[k] = g00[k-1]*g01[k-1] + g01[k-1]*g11[k-1];
        g10[k] = g10[k-1]*g00[k-1] + g11[k-1]*g10[k-1];
        g11[k] = g10[k-1]*g01[k-1] + g11[k-1]*g11[k-1];
    }
    float sc00[6], sc01[6], sc10[6], sc11[6];
    #pragma unroll
    for (int k = 0; k < 6; ++k) {
        sc00[k] = (float)g00[k]; sc01[k] = (float)g01[k];
        sc10[k] = (float)g10[k]; sc11[k] = (float)g11[k];
    }
    const float w00 = (float)g00[6], w01 = (float)g01[6];
    const float w10 = (float)g10[6], w11 = (float)g11[6];
    // per-lane matrix A32^lane via bit product (powers of M commute)
    double l00 = 1.0, l01 = 0.0, l10 = 0.0, l11 = 1.0;
    #pragma unroll
    for (int k = 0; k < 6; ++k) {
        if ((lane >> k) & 1) {
            double n00 = g00[k]*l00 + g01[k]*l10, n01 = g00[k]*l01 + g01[k]*l11;
            double n10 = g10[k]*l00 + g11[k]*l10, n11 = g10[k]*l01 + g11[k]*l11;
            l00 = n00; l01 = n01; l10 = n10; l11 = n11;
        }
    }
    const float La00 = (float)l00, La01 = (float)l01;
    const float La10 = (float)l10, La11 = (float)l11;

    float ps = Zr[0];
    float vs = 0.0f;

    float4 r[8];
    {
        const float4* src = (const float4*)Zr;
        #pragma unroll
        for (int i = 0; i < 8; ++i) r[i] = src[i * 128 + tid];
    }

    for (int s = 0; s < NSEC; ++s) {
        // ---- stage prefetched regs into LDS (chunk-transpose) ----
        #pragma unroll
        for (int i = 0; i < 8; ++i) {
            int f = i * 128 + tid;
            int c = f >> 3;
            int j = (f & 7) << 2;
            float* p = buf + c * STRIDE + j;
            p[0] = r[i].x; p[1] = r[i].y; p[2] = r[i].z; p[3] = r[i].w;
        }

        // ---- issue next section's loads (in flight under compute) ----
        if (s + 1 < NSEC) {
            const float4* src = (const float4*)(Zr + (s + 1) * W);
            #pragma unroll
            for (int i = 0; i < 8; ++i) r[i] = src[i * 128 + tid];
        }

        __syncthreads();

        // ---- pass A: per-lane chunk offset from s=(0,0); keep z in regs ----
        float c32[L];
        float bp, bv;
        {
            float p = 0.0f, v = 0.0f;
            const float* zc = buf + tid * STRIDE;
            #pragma unroll
            for (int j = 0; j < L; ++j) {
                float z    = zc[j];
                c32[j]     = z;
                float diff = z - p;
                float x    = p + A_CONST * diff;
                v += B_CONST * diff;
                p  = x + v;
            }
            bp = p; bv = v;
        }

        // ---- constant-matrix Kogge-Stone scan of offsets ----
        float sb0 = bp, sb1 = bv;
        #pragma unroll
        for (int k = 0; k < 6; ++k) {
            const int d = 1 << k;
            float ob0 = __shfl_up(sb0, d);
            float ob1 = __shfl_up(sb1, d);
            if (lane >= d) {
                sb0 = sc00[k]*ob0 + sc01[k]*ob1 + sb0;
                sb1 = sc10[k]*ob0 + sc11[k]*ob1 + sb1;
            }
        }

        float eb0 = __shfl_up(sb0, 1);
        float eb1 = __shfl_up(sb1, 1);
        if (lane == 0) { eb0 = 0.0f; eb1 = 0.0f; }

        float i0 = __shfl(sb0, 63);
        float i1 = __shfl(sb1, 63);
        if (lane == 0) { scr[wid * 2] = i0; scr[wid * 2 + 1] = i1; }
        __syncthreads();

        const float I00 = scr[0], I01 = scr[1];
        const float I10 = scr[2], I11 = scr[3];

        const float T0 = w00*ps + w01*vs + I00;   // wave-1 entry state
        const float T1 = w10*ps + w11*vs + I01;
        const float S0 = wid ? T0 : ps;
        const float S1 = wid ? T1 : vs;
        const float np = w00*T0 + w01*T1 + I10;   // next section start
        const float nv = w10*T0 + w11*T1 + I11;

        float p = La00*S0 + La01*S1 + eb0;
        float v = La10*S0 + La11*S1 + eb1;

        // ---- pass B: replay chunk from regs, write x to LDS ----
        {
            float* zc = buf + tid * STRIDE;
            #pragma unroll
            for (int j = 0; j < L; ++j) {
                float z    = c32[j];
                float diff = z - p;
                float x    = p + A_CONST * diff;
                v += B_CONST * diff;
                p  = x + v;
                zc[j] = x;
            }
        }

        __syncthreads();

        // ---- unload: coalesced stores, no-allocate policy (sc0 sc1 nt) ----
        {
            float* dstf = Xr + s * W;
            #pragma unroll
            for (int i = 0; i < 8; ++i) {
                int f = i * 128 + tid;
                int c = f >> 3;
                int j = (f & 7) << 2;
                const float* q = buf + c * STRIDE + j;
                vfloat4 v4 = { q[0], q[1], q[2], q[3] };
                float* addr = dstf + f * 4;
                asm volatile("global_store_dwordx4 %0, %1, off sc0 sc1 nt"
                             :: "v"(addr), "v"(v4) : "memory");
            }
        }

        __syncthreads();   // protect buf before next section's staging

        ps = np; vs = nv;
    }
}

extern "C" void kernel_launch(void* const* d_in, const int* in_sizes, int n_in,
                              void* d_out, int out_size, void* d_ws, size_t ws_size,
                              hipStream_t stream) {
    const float* Z = (const float*)d_in[0];
    float*       X = (float*)d_out;
    dim3 grid(ROWS), block(128);
    hipLaunchKernelGGL(kalman_kernel, grid, block, 0, stream, Z, X);
}